// Round 5
// baseline (176.797 us; speedup 1.0000x reference)
//
#include <hip/hip_runtime.h>

// MHSA: B=2, S=2048, D=1024, H=16, hd=64. fp32 in/out, bf16 MFMA internally.
// cvt(all) -> gemm_qkv(Q*SC,K + V^T split, LDS dbuf) -> flash attn (S^T, 4-wave blocks:
//             2qg x 2kg, Bq=64, 4 indep barrier domains/CU, P in registers via permlane,
//             XCD-local grid) -> gemm_out(+bias, LDS dbuf)

typedef __attribute__((ext_vector_type(8))) short short8;
typedef __attribute__((ext_vector_type(4))) float f32x4;
typedef __attribute__((ext_vector_type(2))) unsigned int uint32x2;
typedef unsigned short ushort_t;
typedef unsigned int uint32;

#define AS1 __attribute__((address_space(1)))
#define AS3 __attribute__((address_space(3)))

__device__ __forceinline__ void gload_lds16(const void* gp, void* lp) {
    __builtin_amdgcn_global_load_lds((const AS1 void*)gp, (AS3 void*)lp, 16, 0, 0);
}

#if __has_builtin(__builtin_amdgcn_exp2f)
#define EXP2F(x) __builtin_amdgcn_exp2f(x)
#else
#define EXP2F(x) exp2f(x)
#endif

__device__ __forceinline__ uint32 rhu(float f) { return __float_as_uint(f) + 0x8000u; }
#if __has_builtin(__builtin_amdgcn_perm)
__device__ __forceinline__ uint32 pk2bf(float a, float b) {
    return __builtin_amdgcn_perm(rhu(b), rhu(a), 0x07060302u);
}
#else
__device__ __forceinline__ uint32 pk2bf(float a, float b) {
    return (rhu(a) >> 16) | (rhu(b) & 0xffff0000u);
}
#endif
__device__ __forceinline__ ushort_t f2bf(float f) { return (ushort_t)(rhu(f) >> 16); }

// gfx950 cross-lane row swaps (VALU, no LDS). plane32: vdst lanes32-63 <-> vsrc lanes0-31.
// plane16: vdst odd 16-rows <-> vsrc even 16-rows.
#if __has_builtin(__builtin_amdgcn_permlane32_swap)
__device__ __forceinline__ void plane32(uint32& a, uint32& b) {
    uint32x2 r = __builtin_amdgcn_permlane32_swap(a, b, false, false);
    a = r[0]; b = r[1];
}
#else
__device__ __forceinline__ void plane32(uint32& a, uint32& b) {
    asm("v_permlane32_swap_b32 %0, %1" : "+v"(a), "+v"(b));
}
#endif
#if __has_builtin(__builtin_amdgcn_permlane16_swap)
__device__ __forceinline__ void plane16(uint32& a, uint32& b) {
    uint32x2 r = __builtin_amdgcn_permlane16_swap(a, b, false, false);
    a = r[0]; b = r[1];
}
#else
__device__ __forceinline__ void plane16(uint32& a, uint32& b) {
    asm("v_permlane16_swap_b32 %0, %1" : "+v"(a), "+v"(b));
}
#endif

// ---------------- fused fp32 -> bf16 convert ----------------
__global__ void cvt_all(const float* __restrict__ x, ushort_t* __restrict__ xb,
                        const float* __restrict__ wq, ushort_t* __restrict__ wqb,
                        const float* __restrict__ wo, ushort_t* __restrict__ wob) {
    int blk = blockIdx.x;
    const float* in; ushort_t* out;
    if (blk < 4096)      { in = x;  out = xb;  }
    else if (blk < 7168) { in = wq; out = wqb; blk -= 4096; }
    else                 { in = wo; out = wob; blk -= 7168; }
    const int i = (blk * 256 + threadIdx.x) * 4;
    const float4 v = *(const float4*)(in + i);
    uint2 pk;
    pk.x = pk2bf(v.x, v.y);
    pk.y = pk2bf(v.z, v.w);
    *(uint2*)(out + i) = pk;
}

// ---------------- GEMM1: qkv = x·Wqkv^T, 128x128 tile, BK=32, dbuf ----------------
__global__ __launch_bounds__(256, 2)
void gemm_qkv(const ushort_t* __restrict__ A, const ushort_t* __restrict__ B,
              ushort_t* __restrict__ Cb, ushort_t* __restrict__ vT,
              int M, int N, int K, int ldc, float qScale) {
    __shared__ ushort_t lA[2][128 * 32];
    __shared__ ushort_t lB[2][128 * 32];
    const int tid = threadIdx.x;
    const int wave = tid >> 6, lane = tid & 63;
    const int quad = lane >> 4, l16 = lane & 15;
    const int wr = wave >> 1, wc = wave & 1;
    const int mBase = blockIdx.y * 128, nBase = blockIdx.x * 128;

    f32x4 acc[4][4];
#pragma unroll
    for (int i = 0; i < 4; i++)
#pragma unroll
        for (int j = 0; j < 4; j++) acc[i][j] = (f32x4){0.f, 0.f, 0.f, 0.f};

    const int ar = tid >> 2;
    const int ac = (((tid & 3) ^ ((ar >> 1) & 3)) * 8);
    const int rsw = ((l16 >> 1) & 3);

    const ushort_t* aptr = A + (size_t)(mBase + ar) * K + ac;
    const ushort_t* bptr = B + (size_t)(nBase + ar) * K + ac;

#define G1_STAGE(buf, k0)                                                            \
    {                                                                                \
        _Pragma("unroll") for (int c = 0; c < 2; c++) {                              \
            gload_lds16(aptr + (size_t)(c * 64) * K + (k0), lA[buf] + c * 2048 + wave * 512); \
            gload_lds16(bptr + (size_t)(c * 64) * K + (k0), lB[buf] + c * 2048 + wave * 512); \
        }                                                                            \
    }

    G1_STAGE(0, 0);
    for (int k0 = 0; k0 < K; k0 += 32) {
        const int cur = (k0 >> 5) & 1;
        __syncthreads();
        if (k0 + 32 < K) G1_STAGE(cur ^ 1, k0 + 32);

        short8 af[4], bf[4];
#pragma unroll
        for (int i = 0; i < 4; i++)
            af[i] = *(const short8*)(lA[cur] + (wr * 64 + i * 16 + l16) * 32 + ((quad ^ rsw) * 8));
#pragma unroll
        for (int j = 0; j < 4; j++)
            bf[j] = *(const short8*)(lB[cur] + (wc * 64 + j * 16 + l16) * 32 + ((quad ^ rsw) * 8));
#pragma unroll
        for (int i = 0; i < 4; i++)
#pragma unroll
            for (int j = 0; j < 4; j++)
                acc[i][j] = __builtin_amdgcn_mfma_f32_16x16x32_bf16(af[i], bf[j], acc[i][j], 0, 0, 0);
    }

    if (nBase >= 2048) {
#pragma unroll
        for (int i = 0; i < 4; i++)
#pragma unroll
            for (int j = 0; j < 4; j++) {
                const int row0 = mBase + wr * 64 + i * 16 + quad * 4;
                const int col = nBase + wc * 64 + j * 16 + l16 - 2048;
                const int b = row0 >> 11, s0 = row0 & 2047;
                uint2 pk;
                pk.x = pk2bf(acc[i][j][0], acc[i][j][1]);
                pk.y = pk2bf(acc[i][j][2], acc[i][j][3]);
                *(uint2*)(vT + ((size_t)(b * 16) * 64 + col) * 2048 + s0) = pk;
            }
        return;
    }
    const float cs = (nBase < 1024) ? qScale : 1.0f;
#pragma unroll
    for (int i = 0; i < 4; i++)
#pragma unroll
        for (int j = 0; j < 4; j++)
#pragma unroll
            for (int r = 0; r < 4; r++) {
                const int row = mBase + wr * 64 + i * 16 + quad * 4 + r;
                const int col = nBase + wc * 64 + j * 16 + l16;
                Cb[(size_t)row * ldc + col] = f2bf(acc[i][j][r] * cs);
            }
}

// ---------------- GEMM2: out = o·Wout^T + bias, 64x128 tile, BK=64, dbuf ----------------
__global__ __launch_bounds__(256, 2)
void gemm_out(const ushort_t* __restrict__ A, const ushort_t* __restrict__ B,
              float* __restrict__ Cf, const float* __restrict__ bias,
              int M, int N, int K) {
    __shared__ ushort_t lA[2][64 * 64];
    __shared__ ushort_t lB[2][128 * 64];
    const int tid = threadIdx.x;
    const int wave = tid >> 6, lane = tid & 63;
    const int quad = lane >> 4, l16 = lane & 15;
    const int mBase = blockIdx.y * 64, nBase = blockIdx.x * 128;

    f32x4 acc[4][2];
#pragma unroll
    for (int i = 0; i < 4; i++)
#pragma unroll
        for (int j = 0; j < 2; j++) acc[i][j] = (f32x4){0.f, 0.f, 0.f, 0.f};

    const int sr = tid >> 3;
    const int sc = ((tid & 7) ^ (sr & 7)) * 8;
    const int swz = l16 & 7;

    const ushort_t* aptr = A + (size_t)(mBase + sr) * K + sc;
    const ushort_t* bptr = B + (size_t)(nBase + sr) * K + sc;

#define G2_STAGE(buf, k0)                                                              \
    {                                                                                  \
        _Pragma("unroll") for (int c = 0; c < 2; c++)                                  \
            gload_lds16(aptr + (size_t)(c * 32) * K + (k0), lA[buf] + c * 2048 + wave * 512); \
        _Pragma("unroll") for (int c = 0; c < 4; c++)                                  \
            gload_lds16(bptr + (size_t)(c * 32) * K + (k0), lB[buf] + c * 2048 + wave * 512); \
    }

    G2_STAGE(0, 0);
    for (int k0 = 0; k0 < K; k0 += 64) {
        const int cur = (k0 >> 6) & 1;
        __syncthreads();
        if (k0 + 64 < K) G2_STAGE(cur ^ 1, k0 + 64);

#pragma unroll
        for (int ks = 0; ks < 2; ks++) {
            short8 af[4], bf[2];
#pragma unroll
            for (int i = 0; i < 4; i++)
                af[i] = *(const short8*)(lA[cur] + (i * 16 + l16) * 64 + (((ks * 4 + quad) ^ swz) * 8));
#pragma unroll
            for (int j = 0; j < 2; j++)
                bf[j] = *(const short8*)(lB[cur] + (wave * 32 + j * 16 + l16) * 64 + (((ks * 4 + quad) ^ swz) * 8));
#pragma unroll
            for (int i = 0; i < 4; i++)
#pragma unroll
                for (int j = 0; j < 2; j++)
                    acc[i][j] = __builtin_amdgcn_mfma_f32_16x16x32_bf16(af[i], bf[j], acc[i][j], 0, 0, 0);
        }
    }

#pragma unroll
    for (int i = 0; i < 4; i++)
#pragma unroll
        for (int j = 0; j < 2; j++)
#pragma unroll
            for (int r = 0; r < 4; r++) {
                const int row = mBase + i * 16 + quad * 4 + r;
                const int col = nBase + wave * 32 + j * 16 + l16;
                Cf[(size_t)row * N + col] = acc[i][j][r] + bias[col];
            }
}

// ---------------- fused flash attention ----------------
// 256 thr = 4 waves = 2 qg x 2 kg; Bq=64, wave owns 32 q x 32 keys of each 64-key tile.
// grid (32,32) = 1024 blocks -> 4 blocks/CU = 4 INDEPENDENT barrier domains per CU (was 2;
// same 16 waves/CU — the change is sync granularity, the untested axis after r0-r4 showed
// in-block TLP, chain-break, LDS-conflict and L2 fixes all leave ~45us intact).
// x=bh: linear id = bh + 32*qRow -> XCD = bh%8, K/V L2-resident per XCD (r4-verified).
// P in registers via exp2+pk2bf+permlane32/16 (r4-verified, conflicts=0). No PV lag (null).
// LDS 32KB: K dbuf [0,8192) | V dbuf [8192,16384) ushorts. Q (64x64) staged pre-loop
// overlaying K buf0; epilogue f32 scratch overlays [0,8320) ushorts*2.
__global__ __launch_bounds__(256, 4)
void attn_flash(const ushort_t* __restrict__ qk, const ushort_t* __restrict__ vT,
                ushort_t* __restrict__ o) {
    __shared__ ushort_t smem[16384];

    const int tid = threadIdx.x;
    const int wave = tid >> 6, lane = tid & 63;
    const int quad = lane >> 4, l16 = lane & 15;
    const int qg = wave & 1, kg = wave >> 1;
    const int bh = blockIdx.x, b = bh >> 4, h = bh & 15;
    const size_t rowBase = (size_t)b * 2048;
    const int qCol = h * 64, kCol = 1024 + h * 64;
    const int qRow0 = blockIdx.y * 64;
    const int swz = l16 & 7;

    // staging geometry: 2 passes of 32 rows x 8 chunks (256 thr x 16B = 4KB/pass).
    // pass cc: row = cc*32 + (tid>>3); chunk src col XOR-swizzled so linear LDS dest
    // (region + cc*2048 + wave*512 + lane*8) holds chunk (c ^ (row&7)) — matches reads.
    const int sr0 = tid >> 3;                          // 0..31 (row within pass)
    const int sc = ((tid & 7) ^ (sr0 & 7)) * 8;        // row&7 == sr0&7 (32 ≡ 0 mod 8)

    // ---- stage Q 64x64 (pre-scaled by SC) into K-buf0 region [0,4096), pull B-frags ----
#pragma unroll
    for (int cc = 0; cc < 2; cc++)
        gload_lds16(qk + (rowBase + qRow0 + cc * 32 + sr0) * 2048 + qCol + sc,
                    smem + cc * 2048 + wave * 512);
    __syncthreads();
    short8 qf[2][2];  // [qt][ks]: q = qg*32 + qt*16 + l16
#pragma unroll
    for (int qt = 0; qt < 2; qt++)
#pragma unroll
        for (int ks = 0; ks < 2; ks++)
            qf[qt][ks] = *(const short8*)(smem + (qg * 32 + qt * 16 + l16) * 64 +
                                          (((ks * 4 + quad) ^ swz) * 8));
    __syncthreads();  // all waves' qf reads done before K staging overwrites buf0

    short8 onesA;
#pragma unroll
    for (int i = 0; i < 8; i++) onesA[i] = (short)0x3F80;

    f32x4 oacc[4][2];  // [dt][qt]
    f32x4 lacc[2];     // [qt], entries replicate l
#pragma unroll
    for (int qt = 0; qt < 2; qt++) {
        lacc[qt] = (f32x4){0.f, 0.f, 0.f, 0.f};
#pragma unroll
        for (int dt = 0; dt < 4; dt++) oacc[dt][qt] = (f32x4){0.f, 0.f, 0.f, 0.f};
    }

    const ushort_t* kptr = qk + (rowBase + sr0) * 2048 + kCol + sc;
    const ushort_t* vptr = vT + ((size_t)bh * 64 + sr0) * 2048 + sc;

    f32x4 sacc[2][2];  // [mh][qt]
    short8 pf[2];      // P frag (in-register, rebuilt each iter)

#define AT_STAGE(buf, kt)                                                              \
    {                                                                                  \
        _Pragma("unroll") for (int cc = 0; cc < 2; cc++) {                             \
            gload_lds16(kptr + (size_t)((kt) * 64 + cc * 32) * 2048,                   \
                        smem + (buf) * 4096 + cc * 2048 + wave * 512);                 \
            gload_lds16(vptr + (size_t)(cc * 32) * 2048 + (kt) * 64,                   \
                        smem + 8192 + (buf) * 4096 + cc * 2048 + wave * 512);          \
        }                                                                              \
    }

    // S^T = K·Q^T on 32 keys x 32 q: 4 reads feed 8 MFMA
#define S_BLOCK(cur)                                                                   \
    {                                                                                  \
        const ushort_t* lK = smem + (cur) * 4096;                                      \
        _Pragma("unroll") for (int mh = 0; mh < 2; mh++) {                             \
            const int krow = kg * 32 + mh * 16 + l16;                                  \
            const short8 k0 = *(const short8*)(lK + krow * 64 + ((quad ^ swz) * 8));   \
            const short8 k1 = *(const short8*)(lK + krow * 64 + (((4 + quad) ^ swz) * 8)); \
            __builtin_amdgcn_s_setprio(1);                                             \
            _Pragma("unroll") for (int qt = 0; qt < 2; qt++) {                         \
                f32x4 t = (f32x4){0.f, 0.f, 0.f, 0.f};                                 \
                t = __builtin_amdgcn_mfma_f32_16x16x32_bf16(k0, qf[qt][0], t, 0, 0, 0); \
                t = __builtin_amdgcn_mfma_f32_16x16x32_bf16(k1, qf[qt][1], t, 0, 0, 0); \
                sacc[mh][qt] = t;                                                      \
            }                                                                          \
            __builtin_amdgcn_s_setprio(0);                                             \
        }                                                                              \
    }

    // exp2 + pack + permlane: sacc -> PV B-frag in registers (r4-verified layout).
#define EXPPK_BLOCK(pfdst)                                                             \
    _Pragma("unroll") for (int qt = 0; qt < 2; qt++) {                                 \
        uint32 a0 = pk2bf(EXP2F(sacc[0][qt][0]), EXP2F(sacc[0][qt][1]));               \
        uint32 a1 = pk2bf(EXP2F(sacc[0][qt][2]), EXP2F(sacc[0][qt][3]));               \
        uint32 b0 = pk2bf(EXP2F(sacc[1][qt][0]), EXP2F(sacc[1][qt][1]));               \
        uint32 b1 = pk2bf(EXP2F(sacc[1][qt][2]), EXP2F(sacc[1][qt][3]));               \
        plane32(a0, b0); plane16(a0, b0);                                              \
        plane32(a1, b1); plane16(a1, b1);                                              \
        union { uint32 u[4]; short8 s; } w_;                                           \
        w_.u[0] = a0; w_.u[1] = a1; w_.u[2] = b0; w_.u[3] = b1;                        \
        pfdst[qt] = w_.s;                                                              \
    }

    // P·V (+ones·P for l), same tile, P from registers
#define PV_BLOCK(cur, pfv)                                                             \
    {                                                                                  \
        const ushort_t* lV = smem + 8192 + (cur) * 4096;                               \
        _Pragma("unroll") for (int qt = 0; qt < 2; qt++)                               \
            lacc[qt] = __builtin_amdgcn_mfma_f32_16x16x32_bf16(onesA, pfv[qt], lacc[qt], 0, 0, 0); \
        __builtin_amdgcn_s_setprio(1);                                                 \
        _Pragma("unroll") for (int dt = 0; dt < 4; dt++) {                             \
            const short8 vf = *(const short8*)(lV + (dt * 16 + l16) * 64 +             \
                                               (((kg * 4 + quad) ^ swz) * 8));         \
            _Pragma("unroll") for (int qt = 0; qt < 2; qt++)                           \
                oacc[dt][qt] = __builtin_amdgcn_mfma_f32_16x16x32_bf16(vf, pfv[qt], oacc[dt][qt], 0, 0, 0); \
        }                                                                              \
        __builtin_amdgcn_s_setprio(0);                                                 \
    }

    AT_STAGE(0, 0);
    for (int kt = 0; kt < 32; kt++) {
        const int cur = kt & 1;
        __syncthreads();  // drains tile kt (issued one iteration ago)
        if (kt < 31) AT_STAGE(cur ^ 1, kt + 1);
        S_BLOCK(cur);
        EXPPK_BLOCK(pf);
        PV_BLOCK(cur, pf);
    }

    // ---- epilogue: combine the two key-halves through LDS, write O ----
    __syncthreads();  // all waves done with smem tiles
    float* red = (float*)smem;  // [0,4096) oacc f32, [4096,4160) l  (16.6KB < 32KB)
    if (kg == 1) {
#pragma unroll
        for (int qt = 0; qt < 2; qt++) {
            if (quad == 0) red[4096 + qg * 32 + qt * 16 + l16] = lacc[qt][0];
#pragma unroll
            for (int dt = 0; dt < 4; dt++)
                *(f32x4*)(red + (((qg * 4 + dt) * 2 + qt) * 64 + lane) * 4) = oacc[dt][qt];
        }
    }
    __syncthreads();
    if (kg == 0) {
        float linv[2];
#pragma unroll
        for (int qt = 0; qt < 2; qt++)
            linv[qt] = 1.0f / (lacc[qt][0] + red[4096 + qg * 32 + qt * 16 + l16]);
#pragma unroll
        for (int qt = 0; qt < 2; qt++) {
            const size_t row = rowBase + qRow0 + qg * 32 + qt * 16 + l16;
#pragma unroll
            for (int dt = 0; dt < 4; dt++) {
                const f32x4 r = *(const f32x4*)(red + (((qg * 4 + dt) * 2 + qt) * 64 + lane) * 4);
                uint2 pk;
                pk.x = pk2bf((oacc[dt][qt][0] + r[0]) * linv[qt],
                             (oacc[dt][qt][1] + r[1]) * linv[qt]);
                pk.y = pk2bf((oacc[dt][qt][2] + r[2]) * linv[qt],
                             (oacc[dt][qt][3] + r[3]) * linv[qt]);
                *(uint2*)(o + row * 1024 + h * 64 + dt * 16 + quad * 4) = pk;
            }
        }
    }
}

extern "C" void kernel_launch(void* const* d_in, const int* in_sizes, int n_in,
                              void* d_out, int out_size, void* d_ws, size_t ws_size,
                              hipStream_t stream) {
    const float* x    = (const float*)d_in[0];
    const float* Wqkv = (const float*)d_in[1];
    const float* Wout = (const float*)d_in[2];
    const float* bout = (const float*)d_in[3];
    float* out = (float*)d_out;

    ushort_t* xb    = (ushort_t*)d_ws;                    // 4096*1024
    ushort_t* wqkvb = xb + (size_t)4096 * 1024;           // 3072*1024
    ushort_t* woutb = wqkvb + (size_t)3072 * 1024;        // 1024*1024
    ushort_t* qkb   = woutb + (size_t)1024 * 1024;        // 4096*2048 (Q*SC, K)
    ushort_t* vTb   = qkb + (size_t)4096 * 2048;          // 32*64*2048 (V^T)
    ushort_t* ob    = xb;                                 // alias: x dead after GEMM1

    const float SC = 0.125f * 1.44269504089f;  // SCALE * log2(e)

    cvt_all<<<8192, 256, 0, stream>>>(x, xb, Wqkv, wqkvb, Wout, woutb);
    gemm_qkv<<<dim3(24, 32), 256, 0, stream>>>(xb, wqkvb, qkb, vTb, 4096, 3072, 1024, 2048, SC);
    // grid (32,32): x=bh -> linear id = bh + 32*qRow -> XCD = bh%8 (K/V L2-resident per XCD);
    // 1024 blocks = 4 independent barrier domains per CU.
    attn_flash<<<dim3(32, 32), 256, 0, stream>>>(qkb, vTb, ob);
    gemm_out<<<dim3(8, 64), 256, 0, stream>>>(ob, woutb, out, bout, 4096, 1024, 1024);
}

// Round 6
// 169.611 us; speedup vs baseline: 1.0424x; 1.0424x over previous
//
#include <hip/hip_runtime.h>

// MHSA: B=2, S=2048, D=1024, H=16, hd=64. fp32 in/out, bf16 MFMA internally.
// cvt(all) -> gemm_qkv (256x256 tile, BK=32, 4-deep LDS ring, counted vmcnt(8), raw barriers)
//          -> flash attn (r4 version: 8-wave 4qgx2kg, P in registers, XCD-local grid)
//          -> gemm_out(+bias, LDS dbuf)

typedef __attribute__((ext_vector_type(8))) short short8;
typedef __attribute__((ext_vector_type(4))) float f32x4;
typedef __attribute__((ext_vector_type(2))) unsigned int uint32x2;
typedef unsigned short ushort_t;
typedef unsigned int uint32;

#define AS1 __attribute__((address_space(1)))
#define AS3 __attribute__((address_space(3)))

__device__ __forceinline__ void gload_lds16(const void* gp, void* lp) {
    __builtin_amdgcn_global_load_lds((const AS1 void*)gp, (AS3 void*)lp, 16, 0, 0);
}

#if __has_builtin(__builtin_amdgcn_exp2f)
#define EXP2F(x) __builtin_amdgcn_exp2f(x)
#else
#define EXP2F(x) exp2f(x)
#endif

__device__ __forceinline__ uint32 rhu(float f) { return __float_as_uint(f) + 0x8000u; }
#if __has_builtin(__builtin_amdgcn_perm)
__device__ __forceinline__ uint32 pk2bf(float a, float b) {
    return __builtin_amdgcn_perm(rhu(b), rhu(a), 0x07060302u);
}
#else
__device__ __forceinline__ uint32 pk2bf(float a, float b) {
    return (rhu(a) >> 16) | (rhu(b) & 0xffff0000u);
}
#endif
__device__ __forceinline__ ushort_t f2bf(float f) { return (ushort_t)(rhu(f) >> 16); }

// gfx950 cross-lane row swaps (VALU, no LDS).
#if __has_builtin(__builtin_amdgcn_permlane32_swap)
__device__ __forceinline__ void plane32(uint32& a, uint32& b) {
    uint32x2 r = __builtin_amdgcn_permlane32_swap(a, b, false, false);
    a = r[0]; b = r[1];
}
#else
__device__ __forceinline__ void plane32(uint32& a, uint32& b) {
    asm("v_permlane32_swap_b32 %0, %1" : "+v"(a), "+v"(b));
}
#endif
#if __has_builtin(__builtin_amdgcn_permlane16_swap)
__device__ __forceinline__ void plane16(uint32& a, uint32& b) {
    uint32x2 r = __builtin_amdgcn_permlane16_swap(a, b, false, false);
    a = r[0]; b = r[1];
}
#else
__device__ __forceinline__ void plane16(uint32& a, uint32& b) {
    asm("v_permlane16_swap_b32 %0, %1" : "+v"(a), "+v"(b));
}
#endif

// ---------------- fused fp32 -> bf16 convert ----------------
__global__ void cvt_all(const float* __restrict__ x, ushort_t* __restrict__ xb,
                        const float* __restrict__ wq, ushort_t* __restrict__ wqb,
                        const float* __restrict__ wo, ushort_t* __restrict__ wob) {
    int blk = blockIdx.x;
    const float* in; ushort_t* out;
    if (blk < 4096)      { in = x;  out = xb;  }
    else if (blk < 7168) { in = wq; out = wqb; blk -= 4096; }
    else                 { in = wo; out = wob; blk -= 7168; }
    const int i = (blk * 256 + threadIdx.x) * 4;
    const float4 v = *(const float4*)(in + i);
    uint2 pk;
    pk.x = pk2bf(v.x, v.y);
    pk.y = pk2bf(v.z, v.w);
    *(uint2*)(out + i) = pk;
}

// ---------------- GEMM1: qkv = x·Wqkv^T ----------------
// 256x256 tile, BK=32, M=4096 N=3072 K=1024. 512 thr = 8 waves (2M x 4N), per-wave 128x64.
// LDS: 4-slot ring of (A 16KB + B 16KB) = 128KB; 1 block/CU.
// Schedule per K-step t: { vmcnt(8); s_barrier; stage(t+3) -> slot (t+3)&3; compute slot t&3 }.
// vmcnt(8) = 2 stages (t+1,t+2; 4 loads/thread each) stay in flight across the barrier —
// never drains to 0 (T4). Invariant: at iter-t wait, stages 0..t+2 issued -> vmcnt(8)
// retires stage t for this wave; barrier propagates to all waves. Stage(t+3) overwrites
// slot (t-1)&3: all waves finished reading it before this barrier (their frag ds_reads are
// lgkm-consumed by MFMA inside compute(t-1)). Epilogue peels t=29/30/31 with vmcnt 8/4/0.
// Fragment algebra (XOR chunk swizzle, staging map, C/vT writes) identical to the verified
// 128x128 kernel, scaled to 8 waves.
__global__ __launch_bounds__(512, 2)
void gemm_qkv(const ushort_t* __restrict__ A, const ushort_t* __restrict__ B,
              ushort_t* __restrict__ Cb, ushort_t* __restrict__ vT, float qScale) {
    __shared__ ushort_t smem[4][16384];  // slot: [0,8192) A(256x32) | [8192,16384) B(256x32)
    const int K = 1024;
    const int tid = threadIdx.x;
    const int wave = tid >> 6, lane = tid & 63;
    const int quad = lane >> 4, l16 = lane & 15;
    const int wr = wave >> 2, wc = wave & 3;

    // bijective XCD swizzle: 192 blocks, 24 per XCD, row-chunked (2 M-rows x 12 N per XCD)
    int bid = blockIdx.x + 12 * blockIdx.y;
    bid = (bid & 7) * 24 + (bid >> 3);
    const int nBase = (bid % 12) * 256, mBase = (bid / 12) * 256;

    f32x4 acc[8][4];
#pragma unroll
    for (int i = 0; i < 8; i++)
#pragma unroll
        for (int j = 0; j < 4; j++) acc[i][j] = (f32x4){0.f, 0.f, 0.f, 0.f};

    const int ar = tid >> 2;                              // 0..127
    const int ac = ((tid & 3) ^ ((ar >> 1) & 3)) * 8;     // XOR chunk pre-swizzle (source)
    const int rsw = (l16 >> 1) & 3;

    const ushort_t* aptr = A + (size_t)(mBase + ar) * K + ac;
    const ushort_t* bptr = B + (size_t)(nBase + ar) * K + ac;

#define G1_STAGE(t)                                                                   \
    {                                                                                 \
        ushort_t* d = &smem[(t) & 3][0];                                              \
        const int k0 = (t) * 32;                                                      \
        gload_lds16(aptr + k0, d + wave * 512);                                       \
        gload_lds16(aptr + (size_t)128 * K + k0, d + 4096 + wave * 512);              \
        gload_lds16(bptr + k0, d + 8192 + wave * 512);                                \
        gload_lds16(bptr + (size_t)128 * K + k0, d + 12288 + wave * 512);             \
    }

#define G1_COMPUTE(t)                                                                 \
    {                                                                                 \
        const ushort_t* lA = &smem[(t) & 3][0];                                       \
        const ushort_t* lB = lA + 8192;                                               \
        short8 af[8], bf[4];                                                          \
        _Pragma("unroll") for (int i = 0; i < 8; i++)                                 \
            af[i] = *(const short8*)(lA + (wr * 128 + i * 16 + l16) * 32 +            \
                                     ((quad ^ rsw) * 8));                             \
        _Pragma("unroll") for (int j = 0; j < 4; j++)                                 \
            bf[j] = *(const short8*)(lB + (wc * 64 + j * 16 + l16) * 32 +             \
                                     ((quad ^ rsw) * 8));                             \
        _Pragma("unroll") for (int i = 0; i < 8; i++)                                 \
            _Pragma("unroll") for (int j = 0; j < 4; j++)                             \
                acc[i][j] = __builtin_amdgcn_mfma_f32_16x16x32_bf16(af[i], bf[j],     \
                                                                    acc[i][j], 0, 0, 0); \
    }

#define G1_SYNC(n)                                                                    \
    asm volatile("s_waitcnt vmcnt(" #n ")" ::: "memory");                             \
    __builtin_amdgcn_s_barrier();                                                     \
    asm volatile("" ::: "memory");

    G1_STAGE(0); G1_STAGE(1); G1_STAGE(2);

#pragma unroll 4
    for (int t = 0; t < 28; ++t) {
        G1_SYNC(8);
        G1_STAGE(t + 3);
        G1_COMPUTE(t);
    }
    { G1_SYNC(8); G1_STAGE(31); G1_COMPUTE(28); }
    { G1_SYNC(8); G1_COMPUTE(29); }
    { G1_SYNC(4); G1_COMPUTE(30); }
    { G1_SYNC(0); G1_COMPUTE(31); }

    // ---- epilogue: cols [0,2048) -> qk bf16 (Q scaled); cols [2048,3072) -> V^T ----
    if (nBase >= 2048) {
#pragma unroll
        for (int i = 0; i < 8; i++)
#pragma unroll
            for (int j = 0; j < 4; j++) {
                const int row0 = mBase + wr * 128 + i * 16 + quad * 4;
                const int col = nBase + wc * 64 + j * 16 + l16 - 2048;
                const int b = row0 >> 11, s0 = row0 & 2047;
                uint2 pk;
                pk.x = pk2bf(acc[i][j][0], acc[i][j][1]);
                pk.y = pk2bf(acc[i][j][2], acc[i][j][3]);
                *(uint2*)(vT + ((size_t)(b * 16) * 64 + col) * 2048 + s0) = pk;
            }
        return;
    }
    const float cs = (nBase < 1024) ? qScale : 1.0f;
#pragma unroll
    for (int i = 0; i < 8; i++)
#pragma unroll
        for (int j = 0; j < 4; j++)
#pragma unroll
            for (int r = 0; r < 4; r++) {
                const int row = mBase + wr * 128 + i * 16 + quad * 4 + r;
                const int col = nBase + wc * 64 + j * 16 + l16;
                Cb[(size_t)row * 2048 + col] = f2bf(acc[i][j][r] * cs);
            }
}

// ---------------- GEMM2: out = o·Wout^T + bias, 64x128 tile, BK=64, dbuf ----------------
__global__ __launch_bounds__(256, 2)
void gemm_out(const ushort_t* __restrict__ A, const ushort_t* __restrict__ B,
              float* __restrict__ Cf, const float* __restrict__ bias,
              int M, int N, int K) {
    __shared__ ushort_t lA[2][64 * 64];
    __shared__ ushort_t lB[2][128 * 64];
    const int tid = threadIdx.x;
    const int wave = tid >> 6, lane = tid & 63;
    const int quad = lane >> 4, l16 = lane & 15;
    const int mBase = blockIdx.y * 64, nBase = blockIdx.x * 128;

    f32x4 acc[4][2];
#pragma unroll
    for (int i = 0; i < 4; i++)
#pragma unroll
        for (int j = 0; j < 2; j++) acc[i][j] = (f32x4){0.f, 0.f, 0.f, 0.f};

    const int sr = tid >> 3;
    const int sc = ((tid & 7) ^ (sr & 7)) * 8;
    const int swz = l16 & 7;

    const ushort_t* aptr = A + (size_t)(mBase + sr) * K + sc;
    const ushort_t* bptr = B + (size_t)(nBase + sr) * K + sc;

#define G2_STAGE(buf, k0)                                                              \
    {                                                                                  \
        _Pragma("unroll") for (int c = 0; c < 2; c++)                                  \
            gload_lds16(aptr + (size_t)(c * 32) * K + (k0), lA[buf] + c * 2048 + wave * 512); \
        _Pragma("unroll") for (int c = 0; c < 4; c++)                                  \
            gload_lds16(bptr + (size_t)(c * 32) * K + (k0), lB[buf] + c * 2048 + wave * 512); \
    }

    G2_STAGE(0, 0);
    for (int k0 = 0; k0 < K; k0 += 64) {
        const int cur = (k0 >> 6) & 1;
        __syncthreads();
        if (k0 + 64 < K) G2_STAGE(cur ^ 1, k0 + 64);

#pragma unroll
        for (int ks = 0; ks < 2; ks++) {
            short8 af[4], bf[2];
#pragma unroll
            for (int i = 0; i < 4; i++)
                af[i] = *(const short8*)(lA[cur] + (i * 16 + l16) * 64 + (((ks * 4 + quad) ^ swz) * 8));
#pragma unroll
            for (int j = 0; j < 2; j++)
                bf[j] = *(const short8*)(lB[cur] + (wave * 32 + j * 16 + l16) * 64 + (((ks * 4 + quad) ^ swz) * 8));
#pragma unroll
            for (int i = 0; i < 4; i++)
#pragma unroll
                for (int j = 0; j < 2; j++)
                    acc[i][j] = __builtin_amdgcn_mfma_f32_16x16x32_bf16(af[i], bf[j], acc[i][j], 0, 0, 0);
        }
    }

#pragma unroll
    for (int i = 0; i < 4; i++)
#pragma unroll
        for (int j = 0; j < 2; j++)
#pragma unroll
            for (int r = 0; r < 4; r++) {
                const int row = mBase + i * 16 + quad * 4 + r;
                const int col = nBase + wave * 32 + j * 16 + l16;
                Cf[(size_t)row * N + col] = acc[i][j][r] + bias[col];
            }
}

// ---------------- fused flash attention (r4 version, 45.4us verified) ----------------
// 512 thr = 8 waves = 4 qg x 2 kg; Bq=128, wave owns 32 q x 32 keys of each 64-key tile.
// grid (32,16): x=bh -> XCD = bh%8: all 16 blocks of one (b,h) share an XCD L2 (FETCH -82%).
// P never touches LDS: exp2+pk2bf+permlane32/16 rebuild the PV B-frag in registers
// (bank conflicts = 0). K dbuf 2x8KB, V 3-buf 3x8KB. 56KB -> 2 blocks/CU.
__global__ __launch_bounds__(512, 4)
void attn_flash(const ushort_t* __restrict__ qk, const ushort_t* __restrict__ vT,
                ushort_t* __restrict__ o) {
    __shared__ ushort_t smem[28672];

    const int tid = threadIdx.x;
    const int wave = tid >> 6, lane = tid & 63;
    const int quad = lane >> 4, l16 = lane & 15;
    const int qg = wave & 3, kg = wave >> 2;
    const int bh = blockIdx.x, b = bh >> 4, h = bh & 15;
    const size_t rowBase = (size_t)b * 2048;
    const int qCol = h * 64, kCol = 1024 + h * 64;
    const int qRow0 = blockIdx.y * 128;
    const int swz = l16 & 7;

    const int sr = tid >> 3;                       // 0..63
    const int sc = ((tid & 7) ^ (sr & 7)) * 8;

    // ---- stage Q 128x64 (pre-scaled by SC) into [20480,28672), pull B-frags ----
#pragma unroll
    for (int cc = 0; cc < 2; cc++)
        gload_lds16(qk + (rowBase + qRow0 + cc * 64 + sr) * 2048 + qCol + sc,
                    smem + 20480 + cc * 4096 + wave * 512);
    __syncthreads();
    short8 qf[2][2];  // [qt][ks]: q = qg*32 + qt*16 + l16
#pragma unroll
    for (int qt = 0; qt < 2; qt++)
#pragma unroll
        for (int ks = 0; ks < 2; ks++)
            qf[qt][ks] = *(const short8*)(smem + 20480 + (qg * 32 + qt * 16 + l16) * 64 +
                                          (((ks * 4 + quad) ^ swz) * 8));

    short8 onesA;
#pragma unroll
    for (int i = 0; i < 8; i++) onesA[i] = (short)0x3F80;

    f32x4 oacc[4][2];  // [dt][qt]
    f32x4 lacc[2];     // [qt]
#pragma unroll
    for (int qt = 0; qt < 2; qt++) {
        lacc[qt] = (f32x4){0.f, 0.f, 0.f, 0.f};
#pragma unroll
        for (int dt = 0; dt < 4; dt++) oacc[dt][qt] = (f32x4){0.f, 0.f, 0.f, 0.f};
    }

    const ushort_t* kptr = qk + (rowBase + sr) * 2048 + kCol + sc;
    const ushort_t* vptr = vT + ((size_t)bh * 64 + sr) * 2048 + sc;

    f32x4 sacc[2][2];
    short8 pfA[2], pfB[2];

#define AT_STAGE(kbi, vbi, kt)                                                         \
    {                                                                                  \
        gload_lds16(kptr + (size_t)((kt) * 64) * 2048, smem + (kbi) * 4096 + wave * 512); \
        gload_lds16(vptr + (kt) * 64, smem + 8192 + (vbi) * 4096 + wave * 512);        \
    }

#define S_BLOCK(cur)                                                                   \
    {                                                                                  \
        const ushort_t* lK = smem + (cur) * 4096;                                      \
        _Pragma("unroll") for (int mh = 0; mh < 2; mh++) {                             \
            const int krow = kg * 32 + mh * 16 + l16;                                  \
            const short8 k0 = *(const short8*)(lK + krow * 64 + ((quad ^ swz) * 8));   \
            const short8 k1 = *(const short8*)(lK + krow * 64 + (((4 + quad) ^ swz) * 8)); \
            __builtin_amdgcn_s_setprio(1);                                             \
            _Pragma("unroll") for (int qt = 0; qt < 2; qt++) {                         \
                f32x4 t = (f32x4){0.f, 0.f, 0.f, 0.f};                                 \
                t = __builtin_amdgcn_mfma_f32_16x16x32_bf16(k0, qf[qt][0], t, 0, 0, 0); \
                t = __builtin_amdgcn_mfma_f32_16x16x32_bf16(k1, qf[qt][1], t, 0, 0, 0); \
                sacc[mh][qt] = t;                                                      \
            }                                                                          \
            __builtin_amdgcn_s_setprio(0);                                             \
        }                                                                              \
    }

#define EXPPK_BLOCK(pfdst)                                                             \
    _Pragma("unroll") for (int qt = 0; qt < 2; qt++) {                                 \
        uint32 a0 = pk2bf(EXP2F(sacc[0][qt][0]), EXP2F(sacc[0][qt][1]));               \
        uint32 a1 = pk2bf(EXP2F(sacc[0][qt][2]), EXP2F(sacc[0][qt][3]));               \
        uint32 b0 = pk2bf(EXP2F(sacc[1][qt][0]), EXP2F(sacc[1][qt][1]));               \
        uint32 b1 = pk2bf(EXP2F(sacc[1][qt][2]), EXP2F(sacc[1][qt][3]));               \
        plane32(a0, b0); plane16(a0, b0);                                              \
        plane32(a1, b1); plane16(a1, b1);                                              \
        union { uint32 u[4]; short8 s; } w_;                                           \
        w_.u[0] = a0; w_.u[1] = a1; w_.u[2] = b0; w_.u[3] = b1;                        \
        pfdst[qt] = w_.s;                                                              \
    }

#define PV_BLOCK(vbi, pf)                                                              \
    {                                                                                  \
        const ushort_t* lV = smem + 8192 + (vbi) * 4096;                               \
        _Pragma("unroll") for (int qt = 0; qt < 2; qt++)                               \
            lacc[qt] = __builtin_amdgcn_mfma_f32_16x16x32_bf16(onesA, pf[qt], lacc[qt], 0, 0, 0); \
        __builtin_amdgcn_s_setprio(1);                                                 \
        _Pragma("unroll") for (int dt = 0; dt < 4; dt++) {                             \
            const short8 vf = *(const short8*)(lV + (dt * 16 + l16) * 64 +             \
                                               (((kg * 4 + quad) ^ swz) * 8));         \
            _Pragma("unroll") for (int qt = 0; qt < 2; qt++)                           \
                oacc[dt][qt] = __builtin_amdgcn_mfma_f32_16x16x32_bf16(vf, pf[qt], oacc[dt][qt], 0, 0, 0); \
        }                                                                              \
        __builtin_amdgcn_s_setprio(0);                                                 \
    }

    AT_STAGE(0, 0, 0);

    __syncthreads();
    AT_STAGE(1, 1, 1);
    S_BLOCK(0);
    EXPPK_BLOCK(pfA);

    int vs = 2, vp = 0;
    for (int kt = 1; kt <= 29; kt += 2) {
        __syncthreads();
        AT_STAGE(0, vs, kt + 1);
        S_BLOCK(1);
        PV_BLOCK(vp, pfA);
        EXPPK_BLOCK(pfB);
        vs = (vs == 2) ? 0 : vs + 1;
        vp = (vp == 2) ? 0 : vp + 1;
        __syncthreads();
        AT_STAGE(1, vs, kt + 2);
        S_BLOCK(0);
        PV_BLOCK(vp, pfB);
        EXPPK_BLOCK(pfA);
        vs = (vs == 2) ? 0 : vs + 1;
        vp = (vp == 2) ? 0 : vp + 1;
    }

    __syncthreads();
    S_BLOCK(1);
    PV_BLOCK(0, pfA);
    EXPPK_BLOCK(pfB);
    PV_BLOCK(1, pfB);

    // ---- epilogue ----
    __syncthreads();
    float* red = (float*)smem;
    if (kg == 1) {
#pragma unroll
        for (int qt = 0; qt < 2; qt++) {
            if (quad == 0) red[8192 + qg * 32 + qt * 16 + l16] = lacc[qt][0];
#pragma unroll
            for (int dt = 0; dt < 4; dt++)
                *(f32x4*)(red + (((qg * 4 + dt) * 2 + qt) * 64 + lane) * 4) = oacc[dt][qt];
        }
    }
    __syncthreads();
    if (kg == 0) {
        float linv[2];
#pragma unroll
        for (int qt = 0; qt < 2; qt++)
            linv[qt] = 1.0f / (lacc[qt][0] + red[8192 + qg * 32 + qt * 16 + l16]);
#pragma unroll
        for (int qt = 0; qt < 2; qt++) {
            const size_t row = rowBase + qRow0 + qg * 32 + qt * 16 + l16;
#pragma unroll
            for (int dt = 0; dt < 4; dt++) {
                const f32x4 r = *(const f32x4*)(red + (((qg * 4 + dt) * 2 + qt) * 64 + lane) * 4);
                uint2 pk;
                pk.x = pk2bf((oacc[dt][qt][0] + r[0]) * linv[qt],
                             (oacc[dt][qt][1] + r[1]) * linv[qt]);
                pk.y = pk2bf((oacc[dt][qt][2] + r[2]) * linv[qt],
                             (oacc[dt][qt][3] + r[3]) * linv[qt]);
                *(uint2*)(o + row * 1024 + h * 64 + dt * 16 + quad * 4) = pk;
            }
        }
    }
}

extern "C" void kernel_launch(void* const* d_in, const int* in_sizes, int n_in,
                              void* d_out, int out_size, void* d_ws, size_t ws_size,
                              hipStream_t stream) {
    const float* x    = (const float*)d_in[0];
    const float* Wqkv = (const float*)d_in[1];
    const float* Wout = (const float*)d_in[2];
    const float* bout = (const float*)d_in[3];
    float* out = (float*)d_out;

    ushort_t* xb    = (ushort_t*)d_ws;                    // 4096*1024
    ushort_t* wqkvb = xb + (size_t)4096 * 1024;           // 3072*1024
    ushort_t* woutb = wqkvb + (size_t)3072 * 1024;        // 1024*1024
    ushort_t* qkb   = woutb + (size_t)1024 * 1024;        // 4096*2048 (Q*SC, K)
    ushort_t* vTb   = qkb + (size_t)4096 * 2048;          // 32*64*2048 (V^T)
    ushort_t* ob    = xb;                                 // alias: x dead after GEMM1

    const float SC = 0.125f * 1.44269504089f;  // SCALE * log2(e)

    cvt_all<<<8192, 256, 0, stream>>>(x, xb, Wqkv, wqkvb, Wout, woutb);
    // 256x256 tiles: grid 12x16 = 192 blocks (1/CU), 512 threads
    gemm_qkv<<<dim3(12, 16), 512, 0, stream>>>(xb, wqkvb, qkb, vTb, SC);
    // grid (32,16): x=bh -> XCD = bh%8 (K/V L2-resident per XCD)
    attn_flash<<<dim3(32, 16), 512, 0, stream>>>(qkb, vTb, ob);
    gemm_out<<<dim3(8, 64), 256, 0, stream>>>(ob, woutb, out, bout, 4096, 1024, 1024);
}